// Round 1
// baseline (38.541 us; speedup 1.0000x reference)
//
#include <hip/hip_runtime.h>

// CurvatureLoss: out = sum(|lap(pred) - lap(target)| * mask) / (sum(mask) + 1e-8)
// lap is the 3x3 Laplacian [[0,1,0],[1,-4,1],[0,1,0]], zero ("SAME") padding.
// Linearity: lap(pred)-lap(target) == lap(pred-target) -> compute d = pred-target once.

static constexpr int IMG_W = 1024;   // fixed by reference
static constexpr int IMG_H = 1024;   // fixed by reference
static constexpr int TH_ROWS = 16;   // output rows per block
static constexpr int NT = 256;       // threads per block (4 cols/thread at W=1024)

__global__ __launch_bounds__(NT) void curv_partial_kernel(
    const float* __restrict__ pred,
    const float* __restrict__ target,
    const float* __restrict__ mask,
    float* __restrict__ partial,   // [2 * gridDim.x]: (loss_sum, mask_sum) per block
    int H)
{
    __shared__ float sd[3][IMG_W];     // rotating 3-row window of d = pred - target
    __shared__ float wls[NT / 64], wms[NT / 64];

    const int tid = threadIdx.x;
    const int blocksPerImage = H / TH_ROWS;
    const int b  = blockIdx.x / blocksPerImage;
    const int y0 = (blockIdx.x % blocksPerImage) * TH_ROWS;
    const size_t imgOff = (size_t)b * H * IMG_W;
    const int x4 = tid * 4;            // this thread's 4 columns

    float lsum = 0.f, msum = 0.f;

    auto loadRow = [&](int y, int slot) {
        float4 d;
        if (y >= 0 && y < H) {
            const size_t o = imgOff + (size_t)y * IMG_W + x4;
            const float4 p = *reinterpret_cast<const float4*>(pred + o);
            const float4 t = *reinterpret_cast<const float4*>(target + o);
            d = make_float4(p.x - t.x, p.y - t.y, p.z - t.z, p.w - t.w);
        } else {
            d = make_float4(0.f, 0.f, 0.f, 0.f);  // zero padding rows
        }
        *reinterpret_cast<float4*>(&sd[slot][x4]) = d;
    };

    // Prime the window: rows y0-1 and y0.
    loadRow(y0 - 1, 0);
    loadRow(y0,     1);

    for (int r = 0; r < TH_ROWS; ++r) {
        const int y = y0 + r;
        loadRow(y + 1, (r + 2) % 3);
        __syncthreads();

        const float* up = sd[r % 3];
        const float* ce = sd[(r + 1) % 3];
        const float* dn = sd[(r + 2) % 3];

        const float4 m = *reinterpret_cast<const float4*>(mask + imgOff + (size_t)y * IMG_W + x4);

        const float c0 = ce[x4], c1 = ce[x4 + 1], c2 = ce[x4 + 2], c3 = ce[x4 + 3];
        const float left  = (x4 == 0)         ? 0.f : ce[x4 - 1];
        const float right = (x4 + 4 == IMG_W) ? 0.f : ce[x4 + 4];

        const float l0 = up[x4]     + dn[x4]     + left + c1    - 4.f * c0;
        const float l1 = up[x4 + 1] + dn[x4 + 1] + c0   + c2    - 4.f * c1;
        const float l2 = up[x4 + 2] + dn[x4 + 2] + c1   + c3    - 4.f * c2;
        const float l3 = up[x4 + 3] + dn[x4 + 3] + c2   + right - 4.f * c3;

        lsum += fabsf(l0) * m.x + fabsf(l1) * m.y + fabsf(l2) * m.z + fabsf(l3) * m.w;
        msum += m.x + m.y + m.z + m.w;

        __syncthreads();  // before next iteration overwrites the 'up' slot
    }

    // Wave (64-lane) butterfly reduce, then cross-wave via LDS.
    for (int off = 32; off > 0; off >>= 1) {
        lsum += __shfl_down(lsum, off, 64);
        msum += __shfl_down(msum, off, 64);
    }
    const int wave = tid >> 6;
    if ((tid & 63) == 0) { wls[wave] = lsum; wms[wave] = msum; }
    __syncthreads();
    if (tid == 0) {
        float L = 0.f, M = 0.f;
        #pragma unroll
        for (int w = 0; w < NT / 64; ++w) { L += wls[w]; M += wms[w]; }
        partial[2 * (size_t)blockIdx.x]     = L;
        partial[2 * (size_t)blockIdx.x + 1] = M;
    }
}

__global__ __launch_bounds__(256) void curv_final_kernel(
    const float* __restrict__ partial, float* __restrict__ out, int nblocks)
{
    __shared__ float sL[256], sM[256];
    float L = 0.f, M = 0.f;
    for (int i = threadIdx.x; i < nblocks; i += 256) {
        L += partial[2 * (size_t)i];
        M += partial[2 * (size_t)i + 1];
    }
    sL[threadIdx.x] = L; sM[threadIdx.x] = M;
    __syncthreads();
    for (int s = 128; s > 0; s >>= 1) {
        if (threadIdx.x < s) {
            sL[threadIdx.x] += sL[threadIdx.x + s];
            sM[threadIdx.x] += sM[threadIdx.x + s];
        }
        __syncthreads();
    }
    if (threadIdx.x == 0) out[0] = sL[0] / (sM[0] + 1e-8f);
}

extern "C" void kernel_launch(void* const* d_in, const int* in_sizes, int n_in,
                              void* d_out, int out_size, void* d_ws, size_t ws_size,
                              hipStream_t stream) {
    const float* pred   = (const float*)d_in[0];
    const float* target = (const float*)d_in[1];
    const float* mask   = (const float*)d_in[2];
    float* out = (float*)d_out;
    float* partial = (float*)d_ws;

    const int H = IMG_H;
    const int B = in_sizes[0] / (IMG_H * IMG_W);
    const int nblocks = B * (H / TH_ROWS);   // 16 * 64 = 1024

    curv_partial_kernel<<<nblocks, NT, 0, stream>>>(pred, target, mask, partial, H);
    curv_final_kernel<<<1, 256, 0, stream>>>(partial, out, nblocks);
}